// Round 9
// baseline (406.503 us; speedup 1.0000x reference)
//
#include <hip/hip_runtime.h>
#include <hip/hip_bf16.h>
#include <stdint.h>

// GraphNet global block, MI355X.
// Ledger (measured): node+atomics=222us | node-no-atomics=167 | sort stack +79
// | fixed non-node overhead ~180us (invariant R0/R8) | graph2 MFMA ~fast.
// R9: node is latency-bound (all pipes <15%, occ 31%, ~70K cyc/block vs ~9K
// work at 2 blocks/CU). Lever = TLP: ROWS 128->64 (LDS 35->17.7KB),
// __launch_bounds__(256,4) -> 4-5 blocks/CU, and register-batched staging
// (all 8 global loads in flight before LDS stores). Tiling mechanically
// halved from the R0-proven kernel; atomic tail unchanged; prep/graph2 as-is.

#define NNODES 500000
#define NGRAPHS 4096
#define ROWS 64       // node rows per block (R9: halved for occupancy)
#define LDH 136       // padded f16 row stride (272 B: 16B-aligned, conflict-free)

typedef __attribute__((ext_vector_type(8))) _Float16 half8;
typedef __attribute__((ext_vector_type(4))) float floatx4;

// ---------------- prep: transpose all six weights to f16 [N][K] -------------
__global__ void prep_kernel(const float* __restrict__ w1, const float* __restrict__ w2,
                            const float* __restrict__ w3, const float* __restrict__ w4,
                            const float* __restrict__ w5, const float* __restrict__ w6,
                            _Float16* __restrict__ w1T, _Float16* __restrict__ w2T,
                            _Float16* __restrict__ w3T, _Float16* __restrict__ w4T,
                            _Float16* __restrict__ w5T, _Float16* __restrict__ w6T) {
    int i = blockIdx.x * 256 + threadIdx.x;   // 0..16383
    if (i < 128 * 128) {
        int n = i >> 7, k = i & 127;
        w1T[i] = (_Float16)w1[k * 128 + n];
        w2T[i] = (_Float16)w2[k * 128 + n];
        w4T[i] = (_Float16)w4[k * 128 + n];
        w5T[i] = (_Float16)w5[k * 128 + n];
    }
    if (i < 64 * 128) {
        int n = i >> 7, k = i & 127;
        w3T[i] = (_Float16)w3[k * 64 + n];
        w6T[i] = (_Float16)w6[k * 64 + n];
    }
}

// ---------------- phase 1: per-node MLP + LN + atomic scatter ---------------
// 64 rows/block, 4 waves. Layers 1-2: wave = (row-half, col-half) of 64x128.
// Layer 3: wave owns 16 rows. Atomic tail identical to R0 (proven).
__global__ __launch_bounds__(256, 4) void node_kernel(
    const float* __restrict__ x, const float* __restrict__ u, const int* __restrict__ batch,
    const _Float16* __restrict__ w1T, const _Float16* __restrict__ w2T,
    const _Float16* __restrict__ w3T,
    const float* __restrict__ b1, const float* __restrict__ b2, const float* __restrict__ b3,
    const float* __restrict__ lng, const float* __restrict__ lnb,
    float* __restrict__ agg)
{
    __shared__ __align__(16) _Float16 hA[ROWS * LDH];   // 17408 B
    __shared__ int sBatch[ROWS];

    const int tid = threadIdx.x;
    const int rowbase = blockIdx.x * ROWS;
    const int wave = tid >> 6;
    const int lane = tid & 63;
    const int q = lane >> 4;      // quad (k-block / row-block selector)
    const int l16 = lane & 15;

    // stage batch ids for the tail (wave 0 only; later barriers give visibility)
    if (tid < ROWS) {
        int gr = rowbase + tid;
        sBatch[tid] = (gr < NNODES) ? batch[gr] : 0;
    }

    // ---- stage h0 = concat(x, u[batch]) as f16: 4 half8 stores per thread ----
    // All 8 global float4 loads issued before any LDS store (latency overlap).
    {
        float4 a[4], b[4];
        int rA[4], cA[4];
        #pragma unroll
        for (int k = 0; k < 4; ++k) {
            int j = tid + k * 256;          // 0..1023
            int r = j >> 4;                 // 0..63
            int c8 = (j & 15) << 3;         // 0,8,...,120
            rA[k] = r; cA[k] = c8;
            int gr = rowbase + r;
            bool valid = gr < NNODES;
            int grc = valid ? gr : 0;
            const float* src;
            if (c8 < 64) {
                src = x + (size_t)grc * 64 + c8;
            } else {
                int g = valid ? batch[gr] : 0;
                src = u + (size_t)g * 64 + (c8 - 64);
            }
            float4 va = ((const float4*)src)[0];
            float4 vb = ((const float4*)src)[1];
            if (!valid) {
                va = make_float4(0.f, 0.f, 0.f, 0.f);
                vb = make_float4(0.f, 0.f, 0.f, 0.f);
            }
            a[k] = va; b[k] = vb;
        }
        #pragma unroll
        for (int k = 0; k < 4; ++k) {
            half8 h;
            h[0] = (_Float16)a[k].x; h[1] = (_Float16)a[k].y;
            h[2] = (_Float16)a[k].z; h[3] = (_Float16)a[k].w;
            h[4] = (_Float16)b[k].x; h[5] = (_Float16)b[k].y;
            h[6] = (_Float16)b[k].z; h[7] = (_Float16)b[k].w;
            *(half8*)(&hA[rA[k] * LDH + cA[k]]) = h;
        }
    }
    __syncthreads();

    // ---- layers 1 & 2: 64x128 @ 128x128, relu, in-place in hA ----
    const int rowg = (wave >> 1) * 32;
    const int colg = (wave & 1) * 64;
    for (int layer = 0; layer < 2; ++layer) {
        const _Float16* wT = layer ? w2T : w1T;
        const float* bias = layer ? b2 : b1;
        floatx4 acc[2][4];
        #pragma unroll
        for (int ct = 0; ct < 4; ++ct) {
            float bv = bias[colg + ct * 16 + l16];
            acc[0][ct] = (floatx4){bv, bv, bv, bv};
            acc[1][ct] = (floatx4){bv, bv, bv, bv};
        }
        half8 bfr[4][4];
        #pragma unroll
        for (int ks = 0; ks < 4; ++ks)
            #pragma unroll
            for (int ct = 0; ct < 4; ++ct)
                bfr[ks][ct] = *(const half8*)(wT + (colg + ct * 16 + l16) * 128 + ks * 32 + q * 8);
        #pragma unroll
        for (int ks = 0; ks < 4; ++ks) {
            half8 af[2];
            #pragma unroll
            for (int rt = 0; rt < 2; ++rt)
                af[rt] = *(const half8*)(&hA[(rowg + rt * 16 + l16) * LDH + ks * 32 + q * 8]);
            #pragma unroll
            for (int rt = 0; rt < 2; ++rt)
                #pragma unroll
                for (int ct = 0; ct < 4; ++ct)
                    acc[rt][ct] = __builtin_amdgcn_mfma_f32_16x16x32_f16(
                        af[rt], bfr[ks][ct], acc[rt][ct], 0, 0, 0);
        }
        __syncthreads();   // all reads of hA complete
        #pragma unroll
        for (int rt = 0; rt < 2; ++rt)
            #pragma unroll
            for (int ct = 0; ct < 4; ++ct)
                #pragma unroll
                for (int j = 0; j < 4; ++j) {
                    float v = acc[rt][ct][j];
                    v = v > 0.f ? v : 0.f;
                    hA[(rowg + rt * 16 + q * 4 + j) * LDH + colg + ct * 16 + l16] = (_Float16)v;
                }
        __syncthreads();   // writes visible
    }

    // ---- layer 3: 64x64 + LN + atomic scatter (wave owns 16 rows) ----
    {
        const int rowg3 = wave * 16;
        floatx4 acc[4];
        #pragma unroll
        for (int ct = 0; ct < 4; ++ct) {
            float bv = b3[ct * 16 + l16];
            acc[ct] = (floatx4){bv, bv, bv, bv};
        }
        half8 bfr[4][4];
        #pragma unroll
        for (int ks = 0; ks < 4; ++ks)
            #pragma unroll
            for (int ct = 0; ct < 4; ++ct)
                bfr[ks][ct] = *(const half8*)(w3T + (ct * 16 + l16) * 128 + ks * 32 + q * 8);
        #pragma unroll
        for (int ks = 0; ks < 4; ++ks) {
            half8 af = *(const half8*)(&hA[(rowg3 + l16) * LDH + ks * 32 + q * 8]);
            #pragma unroll
            for (int ct = 0; ct < 4; ++ct)
                acc[ct] = __builtin_amdgcn_mfma_f32_16x16x32_f16(af, bfr[ks][ct], acc[ct], 0, 0, 0);
        }
        float gct[4], bct[4];
        #pragma unroll
        for (int ct = 0; ct < 4; ++ct) {
            gct[ct] = lng[ct * 16 + l16];
            bct[ct] = lnb[ct * 16 + l16];
        }
        #pragma unroll
        for (int j = 0; j < 4; ++j) {
            int rloc = rowg3 + q * 4 + j;     // quad-uniform row
            float v0 = acc[0][j], v1 = acc[1][j];
            float v2 = acc[2][j], v3 = acc[3][j];
            float s = v0 + v1 + v2 + v3;
            float ss = v0 * v0 + v1 * v1 + v2 * v2 + v3 * v3;
            #pragma unroll
            for (int m = 1; m < 16; m <<= 1) {
                s += __shfl_xor(s, m, 16);
                ss += __shfl_xor(ss, m, 16);
            }
            float mean = s * (1.f / 64.f);
            float var = ss * (1.f / 64.f) - mean * mean;
            float rstd = rsqrtf(var + 1e-5f);
            if (rowbase + rloc < NNODES) {
                float* dst = agg + (size_t)sBatch[rloc] * 64;
                unsafeAtomicAdd(dst + 0 + l16,  (v0 - mean) * rstd * gct[0] + bct[0]);
                unsafeAtomicAdd(dst + 16 + l16, (v1 - mean) * rstd * gct[1] + bct[1]);
                unsafeAtomicAdd(dst + 32 + l16, (v2 - mean) * rstd * gct[2] + bct[2]);
                unsafeAtomicAdd(dst + 48 + l16, (v3 - mean) * rstd * gct[3] + bct[3]);
            }
        }
    }
}

// ---------------- phase 2: per-graph MLP, f16 MFMA (32 blocks x 128 rows) ---
__global__ __launch_bounds__(256, 2) void graph2_kernel(
    const float* __restrict__ u,
    const _Float16* __restrict__ w4T, const _Float16* __restrict__ w5T,
    const _Float16* __restrict__ w6T,
    const float* __restrict__ b4, const float* __restrict__ b5, const float* __restrict__ b6,
    const float* __restrict__ lng, const float* __restrict__ lnb,
    float* __restrict__ out)   // out holds agg on entry; rows block-exclusive
{
    __shared__ __align__(16) _Float16 hA[128 * LDH * 2];   // 128 rows, LDH*2 unused tail pad

    const int tid = threadIdx.x;
    const int rowbase = blockIdx.x * 128;
    const int wave = tid >> 6;
    const int lane = tid & 63;
    const int q = lane >> 4;
    const int l16 = lane & 15;
    const int LDG = 136;   // row stride for this kernel's 128-row tile

    // stage g0 = concat(agg, u) as f16
    for (int i = tid; i < 128 * 16; i += 256) {
        int r = i >> 4, c4 = (i & 15) << 2;
        int g = rowbase + r;
        float4 va = *(const float4*)(out + (size_t)g * 64 + c4);
        _Float16* p = &hA[r * LDG + c4];
        p[0] = (_Float16)va.x; p[1] = (_Float16)va.y;
        p[2] = (_Float16)va.z; p[3] = (_Float16)va.w;
        float4 vu = *(const float4*)(u + (size_t)g * 64 + c4);
        _Float16* p2 = &hA[r * LDG + 64 + c4];
        p2[0] = (_Float16)vu.x; p2[1] = (_Float16)vu.y;
        p2[2] = (_Float16)vu.z; p2[3] = (_Float16)vu.w;
    }
    __syncthreads();

    // ---- layers 4 & 5: 128x128, relu, in-place ----
    const int rowg = (wave >> 1) * 64;
    const int colg = (wave & 1) * 64;
    for (int layer = 0; layer < 2; ++layer) {
        const _Float16* wT = layer ? w5T : w4T;
        const float* bias = layer ? b5 : b4;
        floatx4 acc[4][4];
        #pragma unroll
        for (int ct = 0; ct < 4; ++ct) {
            float bv = bias[colg + ct * 16 + l16];
            #pragma unroll
            for (int rt = 0; rt < 4; ++rt) acc[rt][ct] = (floatx4){bv, bv, bv, bv};
        }
        half8 bfr[4][4];
        #pragma unroll
        for (int ks = 0; ks < 4; ++ks)
            #pragma unroll
            for (int ct = 0; ct < 4; ++ct)
                bfr[ks][ct] = *(const half8*)(wT + (colg + ct * 16 + l16) * 128 + ks * 32 + q * 8);
        #pragma unroll
        for (int ks = 0; ks < 4; ++ks) {
            half8 af[4];
            #pragma unroll
            for (int rt = 0; rt < 4; ++rt)
                af[rt] = *(const half8*)(&hA[(rowg + rt * 16 + l16) * LDG + ks * 32 + q * 8]);
            #pragma unroll
            for (int rt = 0; rt < 4; ++rt)
                #pragma unroll
                for (int ct = 0; ct < 4; ++ct)
                    acc[rt][ct] = __builtin_amdgcn_mfma_f32_16x16x32_f16(
                        af[rt], bfr[ks][ct], acc[rt][ct], 0, 0, 0);
        }
        __syncthreads();
        #pragma unroll
        for (int rt = 0; rt < 4; ++rt)
            #pragma unroll
            for (int ct = 0; ct < 4; ++ct)
                #pragma unroll
                for (int j = 0; j < 4; ++j) {
                    float v = acc[rt][ct][j];
                    v = v > 0.f ? v : 0.f;
                    hA[(rowg + rt * 16 + q * 4 + j) * LDG + colg + ct * 16 + l16] = (_Float16)v;
                }
        __syncthreads();
    }

    // ---- layer 6: 128x64 + LN + residual + store ----
    {
        const int rowg3 = wave * 32;
        floatx4 acc[2][4];
        #pragma unroll
        for (int ct = 0; ct < 4; ++ct) {
            float bv = b6[ct * 16 + l16];
            acc[0][ct] = (floatx4){bv, bv, bv, bv};
            acc[1][ct] = (floatx4){bv, bv, bv, bv};
        }
        half8 bfr[4][4];
        #pragma unroll
        for (int ks = 0; ks < 4; ++ks)
            #pragma unroll
            for (int ct = 0; ct < 4; ++ct)
                bfr[ks][ct] = *(const half8*)(w6T + (ct * 16 + l16) * 128 + ks * 32 + q * 8);
        #pragma unroll
        for (int ks = 0; ks < 4; ++ks) {
            half8 af[2];
            #pragma unroll
            for (int rt = 0; rt < 2; ++rt)
                af[rt] = *(const half8*)(&hA[(rowg3 + rt * 16 + l16) * LDG + ks * 32 + q * 8]);
            #pragma unroll
            for (int rt = 0; rt < 2; ++rt)
                #pragma unroll
                for (int ct = 0; ct < 4; ++ct)
                    acc[rt][ct] = __builtin_amdgcn_mfma_f32_16x16x32_f16(
                        af[rt], bfr[ks][ct], acc[rt][ct], 0, 0, 0);
        }
        float gct[4], bct[4];
        #pragma unroll
        for (int ct = 0; ct < 4; ++ct) {
            gct[ct] = lng[ct * 16 + l16];
            bct[ct] = lnb[ct * 16 + l16];
        }
        #pragma unroll
        for (int rt = 0; rt < 2; ++rt)
            #pragma unroll
            for (int j = 0; j < 4; ++j) {
                int rloc = rowg3 + rt * 16 + q * 4 + j;
                size_t g = (size_t)(rowbase + rloc);
                float v0 = acc[rt][0][j], v1 = acc[rt][1][j];
                float v2 = acc[rt][2][j], v3 = acc[rt][3][j];
                float s = v0 + v1 + v2 + v3;
                float ss = v0 * v0 + v1 * v1 + v2 * v2 + v3 * v3;
                #pragma unroll
                for (int m = 1; m < 16; m <<= 1) {
                    s += __shfl_xor(s, m, 16);
                    ss += __shfl_xor(ss, m, 16);
                }
                float mean = s * (1.f / 64.f);
                float var = ss * (1.f / 64.f) - mean * mean;
                float rstd = rsqrtf(var + 1e-5f);
                out[g * 64 + 0 + l16]  = (v0 - mean) * rstd * gct[0] + bct[0] + u[g * 64 + 0 + l16];
                out[g * 64 + 16 + l16] = (v1 - mean) * rstd * gct[1] + bct[1] + u[g * 64 + 16 + l16];
                out[g * 64 + 32 + l16] = (v2 - mean) * rstd * gct[2] + bct[2] + u[g * 64 + 32 + l16];
                out[g * 64 + 48 + l16] = (v3 - mean) * rstd * gct[3] + bct[3] + u[g * 64 + 48 + l16];
            }
    }
}

extern "C" void kernel_launch(void* const* d_in, const int* in_sizes, int n_in,
                              void* d_out, int out_size, void* d_ws, size_t ws_size,
                              hipStream_t stream) {
    const float* x   = (const float*)d_in[0];
    const float* u   = (const float*)d_in[1];
    const int*   bt  = (const int*)d_in[2];
    const float* w1  = (const float*)d_in[3];
    const float* b1  = (const float*)d_in[4];
    const float* w2  = (const float*)d_in[5];
    const float* b2  = (const float*)d_in[6];
    const float* w3  = (const float*)d_in[7];
    const float* b3  = (const float*)d_in[8];
    const float* lng = (const float*)d_in[9];
    const float* lnb = (const float*)d_in[10];
    const float* w4  = (const float*)d_in[11];
    const float* b4  = (const float*)d_in[12];
    const float* w5  = (const float*)d_in[13];
    const float* b5  = (const float*)d_in[14];
    const float* w6  = (const float*)d_in[15];
    const float* b6  = (const float*)d_in[16];
    const float* g2  = (const float*)d_in[17];
    const float* bb2 = (const float*)d_in[18];
    float* out = (float*)d_out;

    // workspace: 6 f16 weight transposes (160 KB)
    _Float16* w1T = (_Float16*)d_ws;
    _Float16* w2T = w1T + 128 * 128;
    _Float16* w3T = w2T + 128 * 128;
    _Float16* w4T = w3T + 64 * 128;
    _Float16* w5T = w4T + 128 * 128;
    _Float16* w6T = w5T + 128 * 128;

    hipMemsetAsync(d_out, 0, (size_t)NGRAPHS * 64 * sizeof(float), stream);
    prep_kernel<<<64, 256, 0, stream>>>(w1, w2, w3, w4, w5, w6,
                                        w1T, w2T, w3T, w4T, w5T, w6T);
    node_kernel<<<(NNODES + ROWS - 1) / ROWS, 256, 0, stream>>>(
        x, u, bt, w1T, w2T, w3T, b1, b2, b3, lng, lnb, out);
    graph2_kernel<<<NGRAPHS / 128, 256, 0, stream>>>(
        u, w4T, w5T, w6T, b4, b5, b6, g2, bb2, out);
}

// Round 10
// 399.324 us; speedup vs baseline: 1.0180x; 1.0180x over previous
//
#include <hip/hip_runtime.h>
#include <hip/hip_bf16.h>
#include <stdint.h>

// GraphNet global block, MI355X.
// Ledger (measured): node+atomics=222us (occ 31%) | node 64-row tile occ 65%
// = 230us (R9: occupancy does NOT help -> throughput wall, not latency) |
// node-no-atomics=167us | fixed non-node ~180us (~100 harness + ~16/launch).
// R10 experiment: distinguish atomic-wall type. 32M atomics hit 4096 x 256B
// lines (~7800 RMW/line). Replicate agg x4 (replica = blockIdx&3): per-line
// traffic /4, aggregate ops unchanged. If per-line serialization -> node
// drops toward 167; if aggregate RMW cap -> unchanged. prep zeroes replicas
// (memset launch dropped; out no longer aliases agg -> graph2 sums replicas).

#define NNODES 500000
#define NGRAPHS 4096
#define ROWS 128      // node rows per block (R0-proven tile)
#define LDH 136       // padded f16 row stride (272 B: 16B-aligned, conflict-free)
#define NREP 4        // agg replicas

typedef __attribute__((ext_vector_type(8))) _Float16 half8;
typedef __attribute__((ext_vector_type(4))) float floatx4;

// ------- prep: transpose six weights to f16 [N][K] + zero agg replicas ------
__global__ void prep_kernel(const float* __restrict__ w1, const float* __restrict__ w2,
                            const float* __restrict__ w3, const float* __restrict__ w4,
                            const float* __restrict__ w5, const float* __restrict__ w6,
                            _Float16* __restrict__ w1T, _Float16* __restrict__ w2T,
                            _Float16* __restrict__ w3T, _Float16* __restrict__ w4T,
                            _Float16* __restrict__ w5T, _Float16* __restrict__ w6T,
                            float* __restrict__ aggR) {
    int i = blockIdx.x * 256 + threadIdx.x;   // 0..16383
    if (i < 128 * 128) {
        int n = i >> 7, k = i & 127;
        w1T[i] = (_Float16)w1[k * 128 + n];
        w2T[i] = (_Float16)w2[k * 128 + n];
        w4T[i] = (_Float16)w4[k * 128 + n];
        w5T[i] = (_Float16)w5[k * 128 + n];
    }
    if (i < 64 * 128) {
        int n = i >> 7, k = i & 127;
        w3T[i] = (_Float16)w3[k * 64 + n];
        w6T[i] = (_Float16)w6[k * 64 + n];
    }
    // zero NREP * NGRAPHS * 64 floats = 262144 float4s; 16 per thread, coalesced
    float4* a4 = (float4*)aggR;
    #pragma unroll
    for (int k = 0; k < 16; ++k)
        a4[i + k * 16384] = make_float4(0.f, 0.f, 0.f, 0.f);
}

// ---------------- phase 1: per-node MLP + LN + atomic scatter (R0) ----------
__global__ __launch_bounds__(256, 2) void node_kernel(
    const float* __restrict__ x, const float* __restrict__ u, const int* __restrict__ batch,
    const _Float16* __restrict__ w1T, const _Float16* __restrict__ w2T,
    const _Float16* __restrict__ w3T,
    const float* __restrict__ b1, const float* __restrict__ b2, const float* __restrict__ b3,
    const float* __restrict__ lng, const float* __restrict__ lnb,
    float* __restrict__ aggR)
{
    __shared__ __align__(16) _Float16 hA[ROWS * LDH];
    __shared__ int sBatch[ROWS];

    const int tid = threadIdx.x;
    const int rowbase = blockIdx.x * ROWS;
    const int wave = tid >> 6;
    const int lane = tid & 63;
    const int q = lane >> 4;      // quad (k-block / row-block selector)
    const int l16 = lane & 15;
    float* agg = aggR + (size_t)(blockIdx.x & (NREP - 1)) * (NGRAPHS * 64);

    // stage batch indices
    for (int r = tid; r < ROWS; r += 256) {
        int gr = rowbase + r;
        sBatch[r] = (gr < NNODES) ? batch[gr] : 0;
    }
    __syncthreads();

    // stage h0 = concat(x, u[batch]) as f16
    for (int i = tid; i < ROWS * 16; i += 256) {
        int r = i >> 4, c4 = (i & 15) << 2;
        int gr = rowbase + r;
        float4 vx = make_float4(0.f, 0.f, 0.f, 0.f);
        if (gr < NNODES) vx = *(const float4*)(x + (size_t)gr * 64 + c4);
        _Float16* p = &hA[r * LDH + c4];
        p[0] = (_Float16)vx.x; p[1] = (_Float16)vx.y;
        p[2] = (_Float16)vx.z; p[3] = (_Float16)vx.w;
        int g = sBatch[r];
        float4 vu = *(const float4*)(u + (size_t)g * 64 + c4);
        _Float16* p2 = &hA[r * LDH + 64 + c4];
        p2[0] = (_Float16)vu.x; p2[1] = (_Float16)vu.y;
        p2[2] = (_Float16)vu.z; p2[3] = (_Float16)vu.w;
    }
    __syncthreads();

    // ---- layers 1 & 2: 128x128, relu, in-place in hA ----
    const int rowg = (wave >> 1) * 64;
    const int colg = (wave & 1) * 64;
    for (int layer = 0; layer < 2; ++layer) {
        const _Float16* wT = layer ? w2T : w1T;
        const float* bias = layer ? b2 : b1;
        floatx4 acc[4][4];
        #pragma unroll
        for (int ct = 0; ct < 4; ++ct) {
            float bv = bias[colg + ct * 16 + l16];
            #pragma unroll
            for (int rt = 0; rt < 4; ++rt) acc[rt][ct] = (floatx4){bv, bv, bv, bv};
        }
        half8 bfr[4][4];
        #pragma unroll
        for (int ks = 0; ks < 4; ++ks)
            #pragma unroll
            for (int ct = 0; ct < 4; ++ct)
                bfr[ks][ct] = *(const half8*)(wT + (colg + ct * 16 + l16) * 128 + ks * 32 + q * 8);
        #pragma unroll
        for (int ks = 0; ks < 4; ++ks) {
            half8 af[4];
            #pragma unroll
            for (int rt = 0; rt < 4; ++rt)
                af[rt] = *(const half8*)(&hA[(rowg + rt * 16 + l16) * LDH + ks * 32 + q * 8]);
            #pragma unroll
            for (int rt = 0; rt < 4; ++rt)
                #pragma unroll
                for (int ct = 0; ct < 4; ++ct)
                    acc[rt][ct] = __builtin_amdgcn_mfma_f32_16x16x32_f16(
                        af[rt], bfr[ks][ct], acc[rt][ct], 0, 0, 0);
        }
        __syncthreads();   // all reads of hA complete
        #pragma unroll
        for (int rt = 0; rt < 4; ++rt)
            #pragma unroll
            for (int ct = 0; ct < 4; ++ct)
                #pragma unroll
                for (int j = 0; j < 4; ++j) {
                    float v = acc[rt][ct][j];
                    v = v > 0.f ? v : 0.f;
                    hA[(rowg + rt * 16 + q * 4 + j) * LDH + colg + ct * 16 + l16] = (_Float16)v;
                }
        __syncthreads();   // writes visible
    }

    // ---- layer 3: 128x64 + LN + atomic scatter (to replica blockIdx&3) ----
    {
        const int rowg3 = wave * 32;   // 4 waves x 32 rows
        floatx4 acc[2][4];
        #pragma unroll
        for (int ct = 0; ct < 4; ++ct) {
            float bv = b3[ct * 16 + l16];
            acc[0][ct] = (floatx4){bv, bv, bv, bv};
            acc[1][ct] = (floatx4){bv, bv, bv, bv};
        }
        half8 bfr[4][4];
        #pragma unroll
        for (int ks = 0; ks < 4; ++ks)
            #pragma unroll
            for (int ct = 0; ct < 4; ++ct)
                bfr[ks][ct] = *(const half8*)(w3T + (ct * 16 + l16) * 128 + ks * 32 + q * 8);
        #pragma unroll
        for (int ks = 0; ks < 4; ++ks) {
            half8 af[2];
            #pragma unroll
            for (int rt = 0; rt < 2; ++rt)
                af[rt] = *(const half8*)(&hA[(rowg3 + rt * 16 + l16) * LDH + ks * 32 + q * 8]);
            #pragma unroll
            for (int rt = 0; rt < 2; ++rt)
                #pragma unroll
                for (int ct = 0; ct < 4; ++ct)
                    acc[rt][ct] = __builtin_amdgcn_mfma_f32_16x16x32_f16(
                        af[rt], bfr[ks][ct], acc[rt][ct], 0, 0, 0);
        }
        float gct[4], bct[4];
        #pragma unroll
        for (int ct = 0; ct < 4; ++ct) {
            gct[ct] = lng[ct * 16 + l16];
            bct[ct] = lnb[ct * 16 + l16];
        }
        #pragma unroll
        for (int rt = 0; rt < 2; ++rt)
            #pragma unroll
            for (int j = 0; j < 4; ++j) {
                int rloc = rowg3 + rt * 16 + q * 4 + j;   // quad-uniform row
                float v0 = acc[rt][0][j], v1 = acc[rt][1][j];
                float v2 = acc[rt][2][j], v3 = acc[rt][3][j];
                float s = v0 + v1 + v2 + v3;
                float ss = v0 * v0 + v1 * v1 + v2 * v2 + v3 * v3;
                #pragma unroll
                for (int m = 1; m < 16; m <<= 1) {
                    s += __shfl_xor(s, m, 16);
                    ss += __shfl_xor(ss, m, 16);
                }
                float mean = s * (1.f / 64.f);
                float var = ss * (1.f / 64.f) - mean * mean;
                float rstd = rsqrtf(var + 1e-5f);
                if (rowbase + rloc < NNODES) {
                    float* dst = agg + (size_t)sBatch[rloc] * 64;
                    unsafeAtomicAdd(dst + 0 + l16,  (v0 - mean) * rstd * gct[0] + bct[0]);
                    unsafeAtomicAdd(dst + 16 + l16, (v1 - mean) * rstd * gct[1] + bct[1]);
                    unsafeAtomicAdd(dst + 32 + l16, (v2 - mean) * rstd * gct[2] + bct[2]);
                    unsafeAtomicAdd(dst + 48 + l16, (v3 - mean) * rstd * gct[3] + bct[3]);
                }
            }
    }
}

// ---------------- phase 2: per-graph MLP, f16 MFMA (32 blocks x 128 rows) ---
__global__ __launch_bounds__(256, 2) void graph2_kernel(
    const float* __restrict__ u, const float* __restrict__ aggR,
    const _Float16* __restrict__ w4T, const _Float16* __restrict__ w5T,
    const _Float16* __restrict__ w6T,
    const float* __restrict__ b4, const float* __restrict__ b5, const float* __restrict__ b6,
    const float* __restrict__ lng, const float* __restrict__ lnb,
    float* __restrict__ out)
{
    __shared__ __align__(16) _Float16 hA[128 * LDH];

    const int tid = threadIdx.x;
    const int rowbase = blockIdx.x * 128;
    const int wave = tid >> 6;
    const int lane = tid & 63;
    const int q = lane >> 4;
    const int l16 = lane & 15;

    // stage g0 = concat(sum of agg replicas, u) as f16
    for (int i = tid; i < 128 * 16; i += 256) {
        int r = i >> 4, c4 = (i & 15) << 2;
        int g = rowbase + r;
        size_t off = (size_t)g * 64 + c4;
        float4 va = *(const float4*)(aggR + off);
        #pragma unroll
        for (int rep = 1; rep < NREP; ++rep) {
            float4 vr = *(const float4*)(aggR + (size_t)rep * (NGRAPHS * 64) + off);
            va.x += vr.x; va.y += vr.y; va.z += vr.z; va.w += vr.w;
        }
        _Float16* p = &hA[r * LDH + c4];
        p[0] = (_Float16)va.x; p[1] = (_Float16)va.y;
        p[2] = (_Float16)va.z; p[3] = (_Float16)va.w;
        float4 vu = *(const float4*)(u + off);
        _Float16* p2 = &hA[r * LDH + 64 + c4];
        p2[0] = (_Float16)vu.x; p2[1] = (_Float16)vu.y;
        p2[2] = (_Float16)vu.z; p2[3] = (_Float16)vu.w;
    }
    __syncthreads();

    // ---- layers 4 & 5: 128x128, relu, in-place ----
    const int rowg = (wave >> 1) * 64;
    const int colg = (wave & 1) * 64;
    for (int layer = 0; layer < 2; ++layer) {
        const _Float16* wT = layer ? w5T : w4T;
        const float* bias = layer ? b5 : b4;
        floatx4 acc[4][4];
        #pragma unroll
        for (int ct = 0; ct < 4; ++ct) {
            float bv = bias[colg + ct * 16 + l16];
            #pragma unroll
            for (int rt = 0; rt < 4; ++rt) acc[rt][ct] = (floatx4){bv, bv, bv, bv};
        }
        half8 bfr[4][4];
        #pragma unroll
        for (int ks = 0; ks < 4; ++ks)
            #pragma unroll
            for (int ct = 0; ct < 4; ++ct)
                bfr[ks][ct] = *(const half8*)(wT + (colg + ct * 16 + l16) * 128 + ks * 32 + q * 8);
        #pragma unroll
        for (int ks = 0; ks < 4; ++ks) {
            half8 af[4];
            #pragma unroll
            for (int rt = 0; rt < 4; ++rt)
                af[rt] = *(const half8*)(&hA[(rowg + rt * 16 + l16) * LDH + ks * 32 + q * 8]);
            #pragma unroll
            for (int rt = 0; rt < 4; ++rt)
                #pragma unroll
                for (int ct = 0; ct < 4; ++ct)
                    acc[rt][ct] = __builtin_amdgcn_mfma_f32_16x16x32_f16(
                        af[rt], bfr[ks][ct], acc[rt][ct], 0, 0, 0);
        }
        __syncthreads();
        #pragma unroll
        for (int rt = 0; rt < 4; ++rt)
            #pragma unroll
            for (int ct = 0; ct < 4; ++ct)
                #pragma unroll
                for (int j = 0; j < 4; ++j) {
                    float v = acc[rt][ct][j];
                    v = v > 0.f ? v : 0.f;
                    hA[(rowg + rt * 16 + q * 4 + j) * LDH + colg + ct * 16 + l16] = (_Float16)v;
                }
        __syncthreads();
    }

    // ---- layer 6: 128x64 + LN + residual + store ----
    {
        const int rowg3 = wave * 32;
        floatx4 acc[2][4];
        #pragma unroll
        for (int ct = 0; ct < 4; ++ct) {
            float bv = b6[ct * 16 + l16];
            acc[0][ct] = (floatx4){bv, bv, bv, bv};
            acc[1][ct] = (floatx4){bv, bv, bv, bv};
        }
        half8 bfr[4][4];
        #pragma unroll
        for (int ks = 0; ks < 4; ++ks)
            #pragma unroll
            for (int ct = 0; ct < 4; ++ct)
                bfr[ks][ct] = *(const half8*)(w6T + (ct * 16 + l16) * 128 + ks * 32 + q * 8);
        #pragma unroll
        for (int ks = 0; ks < 4; ++ks) {
            half8 af[2];
            #pragma unroll
            for (int rt = 0; rt < 2; ++rt)
                af[rt] = *(const half8*)(&hA[(rowg3 + rt * 16 + l16) * LDH + ks * 32 + q * 8]);
            #pragma unroll
            for (int rt = 0; rt < 2; ++rt)
                #pragma unroll
                for (int ct = 0; ct < 4; ++ct)
                    acc[rt][ct] = __builtin_amdgcn_mfma_f32_16x16x32_f16(
                        af[rt], bfr[ks][ct], acc[rt][ct], 0, 0, 0);
        }
        float gct[4], bct[4];
        #pragma unroll
        for (int ct = 0; ct < 4; ++ct) {
            gct[ct] = lng[ct * 16 + l16];
            bct[ct] = lnb[ct * 16 + l16];
        }
        #pragma unroll
        for (int rt = 0; rt < 2; ++rt)
            #pragma unroll
            for (int j = 0; j < 4; ++j) {
                int rloc = rowg3 + rt * 16 + q * 4 + j;
                size_t g = (size_t)(rowbase + rloc);
                float v0 = acc[rt][0][j], v1 = acc[rt][1][j];
                float v2 = acc[rt][2][j], v3 = acc[rt][3][j];
                float s = v0 + v1 + v2 + v3;
                float ss = v0 * v0 + v1 * v1 + v2 * v2 + v3 * v3;
                #pragma unroll
                for (int m = 1; m < 16; m <<= 1) {
                    s += __shfl_xor(s, m, 16);
                    ss += __shfl_xor(ss, m, 16);
                }
                float mean = s * (1.f / 64.f);
                float var = ss * (1.f / 64.f) - mean * mean;
                float rstd = rsqrtf(var + 1e-5f);
                out[g * 64 + 0 + l16]  = (v0 - mean) * rstd * gct[0] + bct[0] + u[g * 64 + 0 + l16];
                out[g * 64 + 16 + l16] = (v1 - mean) * rstd * gct[1] + bct[1] + u[g * 64 + 16 + l16];
                out[g * 64 + 32 + l16] = (v2 - mean) * rstd * gct[2] + bct[2] + u[g * 64 + 32 + l16];
                out[g * 64 + 48 + l16] = (v3 - mean) * rstd * gct[3] + bct[3] + u[g * 64 + 48 + l16];
            }
    }
}

extern "C" void kernel_launch(void* const* d_in, const int* in_sizes, int n_in,
                              void* d_out, int out_size, void* d_ws, size_t ws_size,
                              hipStream_t stream) {
    const float* x   = (const float*)d_in[0];
    const float* u   = (const float*)d_in[1];
    const int*   bt  = (const int*)d_in[2];
    const float* w1  = (const float*)d_in[3];
    const float* b1  = (const float*)d_in[4];
    const float* w2  = (const float*)d_in[5];
    const float* b2  = (const float*)d_in[6];
    const float* w3  = (const float*)d_in[7];
    const float* b3  = (const float*)d_in[8];
    const float* lng = (const float*)d_in[9];
    const float* lnb = (const float*)d_in[10];
    const float* w4  = (const float*)d_in[11];
    const float* b4  = (const float*)d_in[12];
    const float* w5  = (const float*)d_in[13];
    const float* b5  = (const float*)d_in[14];
    const float* w6  = (const float*)d_in[15];
    const float* b6  = (const float*)d_in[16];
    const float* g2  = (const float*)d_in[17];
    const float* bb2 = (const float*)d_in[18];
    float* out = (float*)d_out;

    // workspace: 6 f16 weight transposes (160 KB) + 4 agg replicas (4 MB)
    _Float16* w1T = (_Float16*)d_ws;
    _Float16* w2T = w1T + 128 * 128;
    _Float16* w3T = w2T + 128 * 128;
    _Float16* w4T = w3T + 64 * 128;
    _Float16* w5T = w4T + 128 * 128;
    _Float16* w6T = w5T + 128 * 128;
    float* aggR = (float*)(w6T + 64 * 128);   // byte offset 163840 (16B-aligned)

    prep_kernel<<<64, 256, 0, stream>>>(w1, w2, w3, w4, w5, w6,
                                        w1T, w2T, w3T, w4T, w5T, w6T, aggR);
    node_kernel<<<(NNODES + ROWS - 1) / ROWS, 256, 0, stream>>>(
        x, u, bt, w1T, w2T, w3T, b1, b2, b3, lng, lnb, aggR);
    graph2_kernel<<<NGRAPHS / 128, 256, 0, stream>>>(
        u, aggR, w4T, w5T, w6T, b4, b5, b6, g2, bb2, out);
}